// Round 2
// baseline (318.945 us; speedup 1.0000x reference)
//
#include <hip/hip_runtime.h>

#define N_NODES 50000
#define N_EDGES 800000
#define D 64
#define NUM_LAYERS 4
#define NUM_GRAPHS 128
#define N_ALL (2 * N_NODES)
#define E_ALL (2 * N_EDGES)
#define BSHIFT 9
#define NBUCK ((N_ALL + 511) / 512)     // 196 buckets of 512 dst ids
#define CHUNK 3072                      // edges per bin_scatter block (12/thread)
#define NCHUNK ((E_ALL + CHUNK - 1) / CHUNK)  // 521

// ---------- bf16 helpers (RNE pack, shift unpack) ----------
__device__ __forceinline__ unsigned f2bf(float f) {
    unsigned u = __float_as_uint(f);
    return (u + 0x7FFFu + ((u >> 16) & 1u)) >> 16;
}
__device__ __forceinline__ float bflo(unsigned p) { return __uint_as_float(p << 16); }
__device__ __forceinline__ float bfhi(unsigned p) { return __uint_as_float(p & 0xFFFF0000u); }
__device__ __forceinline__ void acc8(float* a, uint4 v) {
    a[0] += bflo(v.x); a[1] += bfhi(v.x);
    a[2] += bflo(v.y); a[3] += bfhi(v.y);
    a[4] += bflo(v.z); a[5] += bfhi(v.z);
    a[6] += bflo(v.w); a[7] += bfhi(v.w);
}

// ---------- pre-pass: x fp32 -> bf16 (also zeroes bucketTotal + degHist) ----------
__global__ __launch_bounds__(256) void x_to_bf16(const float4* __restrict__ xf,
                                                 uint4* __restrict__ xb,
                                                 int* __restrict__ bucketTotal,
                                                 int* __restrict__ degHist) {
    int t = threadIdx.x;
    if (blockIdx.x == 0 && t < NBUCK) bucketTotal[t] = 0;
    if (blockIdx.x == 1 && t < 128) degHist[t] = 0;
    int idx = blockIdx.x * 256 + t;          // one uint4 (8 bf16) per thread
    if (idx < N_NODES * D / 8) {
        float4 v0 = xf[(size_t)idx * 2];
        float4 v1 = xf[(size_t)idx * 2 + 1];
        uint4 o;
        o.x = f2bf(v0.x) | (f2bf(v0.y) << 16);
        o.y = f2bf(v0.z) | (f2bf(v0.w) << 16);
        o.z = f2bf(v1.x) | (f2bf(v1.y) << 16);
        o.w = f2bf(v1.z) | (f2bf(v1.w) << 16);
        xb[idx] = o;
    }
}

// ---------- pass 0: coarse bucket totals (LDS histogram, tiny global flush) ----------
#define BC_BLOCKS 256
__global__ __launch_bounds__(256) void bucket_count(const int* __restrict__ dR,
                                                    const int* __restrict__ dX,
                                                    int* __restrict__ bucketTotal) {
    __shared__ int lc[NBUCK];
    int t = threadIdx.x;
    for (int j = t; j < NBUCK; j += 256) lc[j] = 0;
    __syncthreads();
    for (int e = blockIdx.x * 256 + t; e < N_EDGES; e += BC_BLOCKS * 256) {
        atomicAdd(&lc[dR[e] >> BSHIFT], 1);
        atomicAdd(&lc[(N_NODES + dX[e]) >> BSHIFT], 1);
    }
    __syncthreads();
    for (int j = t; j < NBUCK; j += 256) {
        int v = lc[j];
        if (v) atomicAdd(&bucketTotal[j], v);
    }
}

// ---------- pass 0b: scan 196 bucket totals (single block) ----------
__global__ __launch_bounds__(256) void bucket_scan(const int* __restrict__ bucketTotal,
                                                   int* __restrict__ bucketBase,
                                                   int* __restrict__ bucketCursor) {
    __shared__ int s[256];
    int t = threadIdx.x;
    int v = (t < NBUCK) ? bucketTotal[t] : 0;
    s[t] = v;
    __syncthreads();
    for (int off = 1; off < 256; off <<= 1) {
        int tv = (t >= off) ? s[t - off] : 0;
        __syncthreads();
        s[t] += tv;
        __syncthreads();
    }
    if (t < NBUCK) {
        int excl = s[t] - v;
        bucketBase[t] = excl;
        bucketCursor[t] = excl;
    }
    if (t == NBUCK - 1) bucketBase[NBUCK] = s[t];   // == E_ALL
}

// ---------- pass 1: bin u32 pairs (d_low9<<16 | src16) by bucket; coalesced runs ----------
__global__ __launch_bounds__(256) void bin_scatter(const int* __restrict__ sR,
                                                   const int* __restrict__ dR,
                                                   const int* __restrict__ sX,
                                                   const int* __restrict__ dX,
                                                   int* __restrict__ bucketCursor,
                                                   unsigned* __restrict__ pairs) {
    __shared__ unsigned lpair[CHUNK];
    __shared__ unsigned char lbuck[CHUNK];
    __shared__ int lcnt[NBUCK];
    __shared__ int lbase[NBUCK];
    __shared__ int gbase[NBUCK];
    __shared__ int sc[256];
    __shared__ int tot;
    int t = threadIdx.x;
    for (int j = t; j < NBUCK; j += 256) lcnt[j] = 0;
    __syncthreads();

    int base = blockIdx.x * CHUNK;
    unsigned myp[12];
    int myr[12], myb[12];
#pragma unroll
    for (int i = 0; i < 12; ++i) {
        int e = base + i * 256 + t;
        if (e < E_ALL) {
            bool isR = (e < N_EDGES);
            int d = isR ? dR[e] : (N_NODES + dX[e - N_EDGES]);
            int s = isR ? sR[e] : sX[e - N_EDGES];
            myp[i] = ((unsigned)(d & 511) << 16) | (unsigned)s;
            myb[i] = d >> BSHIFT;
            myr[i] = atomicAdd(&lcnt[myb[i]], 1);
        }
    }
    __syncthreads();

    int v = (t < NBUCK) ? lcnt[t] : 0;
    sc[t] = v;
    __syncthreads();
    for (int off = 1; off < 256; off <<= 1) {
        int tv = (t >= off) ? sc[t - off] : 0;
        __syncthreads();
        sc[t] += tv;
        __syncthreads();
    }
    if (t < NBUCK) {
        lbase[t] = sc[t] - v;
        if (v > 0) gbase[t] = atomicAdd(&bucketCursor[t], v);
    }
    if (t == NBUCK - 1) tot = sc[t];
    __syncthreads();

#pragma unroll
    for (int i = 0; i < 12; ++i) {
        int e = base + i * 256 + t;
        if (e < E_ALL) {
            int p = lbase[myb[i]] + myr[i];
            lpair[p] = myp[i];
            lbuck[p] = (unsigned char)myb[i];
        }
    }
    __syncthreads();

    int total = tot;
    for (int j = t; j < total; j += 256) {
        int b = lbuck[j];
        pairs[(size_t)gbase[b] + (j - lbase[b])] = lpair[j];
    }
}

// ---------- pass 2: per bucket -- degrees+rowptr in LDS, place col; writes coalesced ----------
// also accumulates the global 64-bin degree histogram (real | expander) for the perm sort
__global__ __launch_bounds__(256) void bucket_place(const unsigned* __restrict__ pairs,
                                                    const int* __restrict__ bucketBase,
                                                    int* __restrict__ rowptr,
                                                    unsigned short* __restrict__ col,
                                                    int* __restrict__ degHist) {
    __shared__ unsigned short scol[10240];
    __shared__ int ldeg[512];
    __shared__ int lcur[512];
    __shared__ int s1[256];
    __shared__ int dh[128];
    int b = blockIdx.x;
    int d0 = b << BSHIFT;
    int nd = min(512, N_ALL - d0);
    int t = threadIdx.x;
    int base = bucketBase[b];
    int cnt = bucketBase[b + 1] - base;
    ldeg[t] = 0; ldeg[t + 256] = 0;
    if (t < 128) dh[t] = 0;
    __syncthreads();
    for (int i = t; i < cnt; i += 256) {
        int dl = pairs[(size_t)base + i] >> 16;
        atomicAdd(&ldeg[dl], 1);
    }
    __syncthreads();
    int v0 = ldeg[2 * t], v1 = ldeg[2 * t + 1];
    int pv = v0 + v1;
    s1[t] = pv;
    __syncthreads();
    for (int off = 1; off < 256; off <<= 1) {
        int tv = (t >= off) ? s1[t - off] : 0;
        __syncthreads();
        s1[t] += tv;
        __syncthreads();
    }
    int before = s1[t] - pv;
    lcur[2 * t] = before;
    lcur[2 * t + 1] = before + v0;
    int n0 = d0 + 2 * t, n1 = d0 + 2 * t + 1;
    if (2 * t < nd) {
        rowptr[n0] = base + before;
        atomicAdd(&dh[min(v0, 63) + ((n0 < N_NODES) ? 0 : 64)], 1);
    }
    if (2 * t + 1 < nd) {
        rowptr[n1] = base + before + v0;
        atomicAdd(&dh[min(v1, 63) + ((n1 < N_NODES) ? 0 : 64)], 1);
    }
    if (b == NBUCK - 1 && t == 0) rowptr[N_ALL] = base + cnt;
    __syncthreads();
    for (int i = t; i < cnt; i += 256) {
        unsigned pr = pairs[(size_t)base + i];
        int dl = pr >> 16;
        int p = atomicAdd(&lcur[dl], 1);
        scol[p] = (unsigned short)(pr & 0xFFFFu);
    }
    __syncthreads();
    for (int i = t; i < cnt; i += 256) col[base + i] = scol[i];
    if (t < 128 && dh[t]) atomicAdd(&degHist[t], dh[t]);
}

// ---------- perm build: descending-degree counting sort (heavy blocks first) ----------
__global__ __launch_bounds__(128) void perm_scan(const int* __restrict__ degHist,
                                                 int* __restrict__ permCursor) {
    int t = threadIdx.x;           // 0..63 real bins, 64..127 expander bins
    int half = t >> 6;
    int bin = t & 63;
    int base = half * 64;
    int sum = 0;
    for (int b2 = bin + 1; b2 < 64; ++b2) sum += degHist[base + b2];  // descending order
    permCursor[t] = sum;
}

__global__ __launch_bounds__(256) void perm_scatter(const int* __restrict__ rowptr,
                                                    int* __restrict__ permCursor,
                                                    int* __restrict__ permR,
                                                    int* __restrict__ permX) {
    __shared__ int lc[128], lb[128];
    int t = threadIdx.x;
    if (t < 128) lc[t] = 0;
    __syncthreads();
    int bins[2], ranks[2];
#pragma unroll
    for (int k = 0; k < 2; ++k) {
        int n = blockIdx.x * 512 + t + k * 256;
        bins[k] = -1;
        if (n < N_ALL) {
            int deg = rowptr[n + 1] - rowptr[n];
            int bin = min(deg, 63) + ((n < N_NODES) ? 0 : 64);
            bins[k] = bin;
            ranks[k] = atomicAdd(&lc[bin], 1);
        }
    }
    __syncthreads();
    if (t < 128 && lc[t]) lb[t] = atomicAdd(&permCursor[t], lc[t]);
    __syncthreads();
#pragma unroll
    for (int k = 0; k < 2; ++k) {
        if (bins[k] >= 0) {
            int n = blockIdx.x * 512 + t + k * 256;
            int pos = lb[bins[k]] + ranks[k];
            if (bins[k] < 64) permR[pos] = n;
            else permX[pos] = n - N_NODES;
        }
    }
}

// ---------- split-edge bf16 gather, unroll 8, degree-sorted node order ----------
__global__ __launch_bounds__(256, 8) void gather_bf16(const uint4* __restrict__ xb,
                                                      uint4* __restrict__ ob,
                                                      const int* __restrict__ rowptr,
                                                      const unsigned short* __restrict__ col,
                                                      const int* __restrict__ perm) {
    int t = threadIdx.x;
    int grp = t >> 4;
    int half = (t >> 3) & 1;
    int ln8 = t & 7;
    int node = perm[blockIdx.x * 16 + grp];   // grid exactly covers 50000
    int beg = rowptr[node], end = rowptr[node + 1];
    int cnt = end - beg;
    int ch = (cnt - half + 1) >> 1;
    const unsigned short* cp = col + beg + half;
    float a[8];
    if (half == 0) {
        uint4 v = xb[(size_t)node * 8 + ln8];
        a[0] = bflo(v.x); a[1] = bfhi(v.x); a[2] = bflo(v.y); a[3] = bfhi(v.y);
        a[4] = bflo(v.z); a[5] = bfhi(v.z); a[6] = bflo(v.w); a[7] = bfhi(v.w);
    } else {
#pragma unroll
        for (int i = 0; i < 8; ++i) a[i] = 0.0f;
    }
    int i = 0;
    for (; i + 8 <= ch; i += 8) {
        int s0 = cp[2 * i],      s1 = cp[2 * i + 2],  s2 = cp[2 * i + 4],  s3 = cp[2 * i + 6];
        int s4 = cp[2 * i + 8],  s5 = cp[2 * i + 10], s6 = cp[2 * i + 12], s7 = cp[2 * i + 14];
        uint4 v0 = xb[(size_t)s0 * 8 + ln8];
        uint4 v1 = xb[(size_t)s1 * 8 + ln8];
        uint4 v2 = xb[(size_t)s2 * 8 + ln8];
        uint4 v3 = xb[(size_t)s3 * 8 + ln8];
        uint4 v4 = xb[(size_t)s4 * 8 + ln8];
        uint4 v5 = xb[(size_t)s5 * 8 + ln8];
        uint4 v6 = xb[(size_t)s6 * 8 + ln8];
        uint4 v7 = xb[(size_t)s7 * 8 + ln8];
        acc8(a, v0); acc8(a, v1); acc8(a, v2); acc8(a, v3);
        acc8(a, v4); acc8(a, v5); acc8(a, v6); acc8(a, v7);
    }
    for (; i + 4 <= ch; i += 4) {
        int s0 = cp[2 * i], s1 = cp[2 * i + 2], s2 = cp[2 * i + 4], s3 = cp[2 * i + 6];
        uint4 v0 = xb[(size_t)s0 * 8 + ln8];
        uint4 v1 = xb[(size_t)s1 * 8 + ln8];
        uint4 v2 = xb[(size_t)s2 * 8 + ln8];
        uint4 v3 = xb[(size_t)s3 * 8 + ln8];
        acc8(a, v0); acc8(a, v1); acc8(a, v2); acc8(a, v3);
    }
    for (; i < ch; ++i) acc8(a, xb[(size_t)cp[2 * i] * 8 + ln8]);
#pragma unroll
    for (int j = 0; j < 8; ++j) a[j] += __shfl_xor(a[j], 8);
    if (half == 0) {
        uint4 o;
        o.x = f2bf(a[0]) | (f2bf(a[1]) << 16);
        o.y = f2bf(a[2]) | (f2bf(a[3]) << 16);
        o.z = f2bf(a[4]) | (f2bf(a[5]) << 16);
        o.w = f2bf(a[6]) | (f2bf(a[7]) << 16);
        ob[(size_t)node * 8 + ln8] = o;
    }
}

// ---------- fused: y = relu( (x + gather(x)) @ W^T + b ), degree-sorted order ----------
__global__ __launch_bounds__(256, 6) void gather_linear(const uint4* __restrict__ xb,
                                                        unsigned short* __restrict__ y,
                                                        const int* __restrict__ rowptr,
                                                        const unsigned short* __restrict__ col,
                                                        const float* __restrict__ W,
                                                        const float* __restrict__ b,
                                                        const int* __restrict__ perm) {
    __shared__ float Wl[64 * 65];   // stride 65: Wl[o*65+k] reads conflict-free
    __shared__ float hl[16 * 64];
    __shared__ int ids[16];
    int t = threadIdx.x;
#pragma unroll
    for (int i = 0; i < 16; ++i) {
        int idx = i * 256 + t;
        Wl[(idx >> 6) * 65 + (idx & 63)] = W[idx];
    }
    int grp = t >> 4;
    int node = perm[blockIdx.x * 16 + grp];   // grid exactly covers 50000
    if ((t & 15) == 0) ids[grp] = node;
    int beg = rowptr[node], end = rowptr[node + 1];
    int half = (t >> 3) & 1;
    int ln8 = t & 7;
    int cnt = end - beg;
    int ch = (cnt - half + 1) >> 1;
    const unsigned short* cp = col + beg + half;
    float a[8];
    if (half == 0) {
        uint4 v = xb[(size_t)node * 8 + ln8];
        a[0] = bflo(v.x); a[1] = bfhi(v.x); a[2] = bflo(v.y); a[3] = bfhi(v.y);
        a[4] = bflo(v.z); a[5] = bfhi(v.z); a[6] = bflo(v.w); a[7] = bfhi(v.w);
    } else {
#pragma unroll
        for (int i = 0; i < 8; ++i) a[i] = 0.0f;
    }
    int i = 0;
    for (; i + 8 <= ch; i += 8) {
        int s0 = cp[2 * i],      s1 = cp[2 * i + 2],  s2 = cp[2 * i + 4],  s3 = cp[2 * i + 6];
        int s4 = cp[2 * i + 8],  s5 = cp[2 * i + 10], s6 = cp[2 * i + 12], s7 = cp[2 * i + 14];
        uint4 v0 = xb[(size_t)s0 * 8 + ln8];
        uint4 v1 = xb[(size_t)s1 * 8 + ln8];
        uint4 v2 = xb[(size_t)s2 * 8 + ln8];
        uint4 v3 = xb[(size_t)s3 * 8 + ln8];
        uint4 v4 = xb[(size_t)s4 * 8 + ln8];
        uint4 v5 = xb[(size_t)s5 * 8 + ln8];
        uint4 v6 = xb[(size_t)s6 * 8 + ln8];
        uint4 v7 = xb[(size_t)s7 * 8 + ln8];
        acc8(a, v0); acc8(a, v1); acc8(a, v2); acc8(a, v3);
        acc8(a, v4); acc8(a, v5); acc8(a, v6); acc8(a, v7);
    }
    for (; i + 4 <= ch; i += 4) {
        int s0 = cp[2 * i], s1 = cp[2 * i + 2], s2 = cp[2 * i + 4], s3 = cp[2 * i + 6];
        uint4 v0 = xb[(size_t)s0 * 8 + ln8];
        uint4 v1 = xb[(size_t)s1 * 8 + ln8];
        uint4 v2 = xb[(size_t)s2 * 8 + ln8];
        uint4 v3 = xb[(size_t)s3 * 8 + ln8];
        acc8(a, v0); acc8(a, v1); acc8(a, v2); acc8(a, v3);
    }
    for (; i < ch; ++i) acc8(a, xb[(size_t)cp[2 * i] * 8 + ln8]);
#pragma unroll
    for (int j = 0; j < 8; ++j) a[j] += __shfl_xor(a[j], 8);
    if (half == 0) {
        float4* hp = (float4*)(hl + grp * 64 + ln8 * 8);
        hp[0] = make_float4(a[0], a[1], a[2], a[3]);
        hp[1] = make_float4(a[4], a[5], a[6], a[7]);
    }
    __syncthreads();

    int o = t & 63, nb = t >> 6;
    float bo = b[o];
    float a0 = bo, a1 = bo, a2 = bo, a3 = bo;
#pragma unroll
    for (int k = 0; k < 64; ++k) {
        float w = Wl[o * 65 + k];
        a0 += hl[(nb     ) * 64 + k] * w;
        a1 += hl[(nb +  4) * 64 + k] * w;
        a2 += hl[(nb +  8) * 64 + k] * w;
        a3 += hl[(nb + 12) * 64 + k] * w;
    }
    int r0 = ids[nb], r1 = ids[nb + 4], r2 = ids[nb + 8], r3 = ids[nb + 12];
    y[(size_t)r0 * 64 + o] = (unsigned short)f2bf(fmaxf(a0, 0.0f));
    y[(size_t)r1 * 64 + o] = (unsigned short)f2bf(fmaxf(a1, 0.0f));
    y[(size_t)r2 * 64 + o] = (unsigned short)f2bf(fmaxf(a2, 0.0f));
    y[(size_t)r3 * 64 + o] = (unsigned short)f2bf(fmaxf(a3, 0.0f));
}

// ---------- pool: batch sorted -> contiguous segments ----------
__device__ __forceinline__ int lower_bound_dev(const int* __restrict__ a, int n, int v) {
    int lo = 0, hi = n;
    while (lo < hi) { int mid = (lo + hi) >> 1; if (a[mid] < v) lo = mid + 1; else hi = mid; }
    return lo;
}

__global__ __launch_bounds__(256) void pool_seg_bf16(const unsigned short* __restrict__ xb,
                                                     const int* __restrict__ batch,
                                                     float* __restrict__ out) {
    int g = blockIdx.x;
    int lo = lower_bound_dev(batch, N_NODES, g);
    int hi = lower_bound_dev(batch, N_NODES, g + 1);
    int lane = threadIdx.x & 63;
    int sub = threadIdx.x >> 6;
    float acc = 0.0f;
    for (int n = lo + sub; n < hi; n += 4)
        acc += __uint_as_float(((unsigned)xb[(size_t)n * 64 + lane]) << 16);
    __shared__ float red[256];
    red[threadIdx.x] = acc;
    __syncthreads();
    if (sub == 0)
        out[(size_t)g * D + lane] = red[lane] + red[64 + lane] + red[128 + lane] + red[192 + lane];
}

// ---------- host ----------
extern "C" void kernel_launch(void* const* d_in, const int* in_sizes, int n_in,
                              void* d_out, int out_size, void* d_ws, size_t ws_size,
                              hipStream_t stream) {
    const float* x_in  = (const float*)d_in[0];
    const int*   ei    = (const int*)d_in[1];
    const int*   eei   = (const int*)d_in[2];
    const int*   batch = (const int*)d_in[3];
    const float* Ws    = (const float*)d_in[4];
    const float* bs    = (const float*)d_in[5];
    float* out = (float*)d_out;

    unsigned short* A = (unsigned short*)d_ws;          // y (bf16) [N*D]
    unsigned short* B = A + (size_t)N_NODES * D;        // x / x' (bf16)
    unsigned short* colAll = B + (size_t)N_NODES * D;   // u16 col [E_ALL]
    unsigned* pairs = (unsigned*)(colAll + E_ALL);      // u32 pairs [E_ALL]
    int* p = (int*)(pairs + E_ALL);
    int* rowptr = p;        p += N_ALL + 1;
    int* bucketTotal = p;   p += NBUCK;
    int* bucketBase = p;    p += NBUCK + 1;
    int* bucketCursor = p;  p += NBUCK;
    int* degHist = p;       p += 128;
    int* permCursor = p;    p += 128;
    int* permR = p;         p += N_NODES;
    int* permX = p;         p += N_NODES;

    const int* e_src = ei;
    const int* e_dst = ei + N_EDGES;
    const int* x_src = eei;
    const int* x_dst = eei + N_EDGES;

    dim3 blk(256);

    // input fp32 -> bf16 (into B); also zeroes bucketTotal + degHist
    const int cgrid = (N_NODES * D / 8 + 255) / 256;   // 1563
    x_to_bf16<<<cgrid, blk, 0, stream>>>((const float4*)x_in, (uint4*)B, bucketTotal, degHist);

    // CSR build: bucket totals -> scan -> bucketed u32-pair sort -> per-bucket rowptr+col
    bucket_count<<<BC_BLOCKS, blk, 0, stream>>>(e_dst, x_dst, bucketTotal);
    bucket_scan<<<1, blk, 0, stream>>>(bucketTotal, bucketBase, bucketCursor);
    bin_scatter<<<NCHUNK, blk, 0, stream>>>(e_src, e_dst, x_src, x_dst, bucketCursor, pairs);
    bucket_place<<<NBUCK, blk, 0, stream>>>(pairs, bucketBase, rowptr, colAll, degHist);

    // degree-descending node permutations (real + expander): counting sort over 64 bins
    perm_scan<<<1, dim3(128), 0, stream>>>(degHist, permCursor);
    perm_scatter<<<NBUCK, blk, 0, stream>>>(rowptr, permCursor, permR, permX);

    const int lgrid = N_NODES / 16;            // 3125, exact

    // all 4 layers uniform bf16: gather_linear(B->A) then expander gather_bf16(A->B)
    for (int i = 0; i < NUM_LAYERS; ++i) {
        gather_linear<<<lgrid, blk, 0, stream>>>((const uint4*)B, A,
                                                 rowptr, colAll,
                                                 Ws + (size_t)i * D * D,
                                                 bs + (size_t)i * D,
                                                 permR);
        gather_bf16<<<lgrid, blk, 0, stream>>>((const uint4*)A, (uint4*)B,
                                               rowptr + N_NODES, colAll,
                                               permX);
    }

    pool_seg_bf16<<<NUM_GRAPHS, blk, 0, stream>>>(B, batch, out);
}

// Round 4
// 307.880 us; speedup vs baseline: 1.0359x; 1.0359x over previous
//
#include <hip/hip_runtime.h>

#define N_NODES 50000
#define N_EDGES 800000
#define D 64
#define NUM_LAYERS 4
#define NUM_GRAPHS 128
#define N_ALL (2 * N_NODES)
#define E_ALL (2 * N_EDGES)
#define BSHIFT 9
#define NBUCK ((N_ALL + 511) / 512)     // 196 buckets of 512 dst ids
#define CHUNK 3072                      // edges per bin_scatter block (12/thread)
#define NCHUNK ((E_ALL + CHUNK - 1) / CHUNK)  // 521

typedef __attribute__((ext_vector_type(8))) short bf16x8;   // 8 bf16 (4 VGPRs)
typedef __attribute__((ext_vector_type(4))) float f32x4;    // MFMA accumulator

// ---------- bf16 helpers (RNE pack, shift unpack) ----------
__device__ __forceinline__ unsigned f2bf(float f) {
    unsigned u = __float_as_uint(f);
    return (u + 0x7FFFu + ((u >> 16) & 1u)) >> 16;
}
__device__ __forceinline__ float bflo(unsigned p) { return __uint_as_float(p << 16); }
__device__ __forceinline__ float bfhi(unsigned p) { return __uint_as_float(p & 0xFFFF0000u); }
__device__ __forceinline__ void acc8(float* a, uint4 v) {
    a[0] += bflo(v.x); a[1] += bfhi(v.x);
    a[2] += bflo(v.y); a[3] += bfhi(v.y);
    a[4] += bflo(v.z); a[5] += bfhi(v.z);
    a[6] += bflo(v.w); a[7] += bfhi(v.w);
}

// ---------- pre-pass: x fp32 -> bf16 (also zeroes bucketTotal, replacing memset) ----------
__global__ __launch_bounds__(256) void x_to_bf16(const float4* __restrict__ xf,
                                                 uint4* __restrict__ xb,
                                                 int* __restrict__ bucketTotal) {
    int t = threadIdx.x;
    if (blockIdx.x == 0 && t < NBUCK) bucketTotal[t] = 0;
    int idx = blockIdx.x * 256 + t;          // one uint4 (8 bf16) per thread
    if (idx < N_NODES * D / 8) {
        float4 v0 = xf[(size_t)idx * 2];
        float4 v1 = xf[(size_t)idx * 2 + 1];
        uint4 o;
        o.x = f2bf(v0.x) | (f2bf(v0.y) << 16);
        o.y = f2bf(v0.z) | (f2bf(v0.w) << 16);
        o.z = f2bf(v1.x) | (f2bf(v1.y) << 16);
        o.w = f2bf(v1.z) | (f2bf(v1.w) << 16);
        xb[idx] = o;
    }
}

// ---------- pass 0: coarse bucket totals (LDS histogram, tiny global flush) ----------
#define BC_BLOCKS 256
__global__ __launch_bounds__(256) void bucket_count(const int* __restrict__ dR,
                                                    const int* __restrict__ dX,
                                                    int* __restrict__ bucketTotal) {
    __shared__ int lc[NBUCK];
    int t = threadIdx.x;
    for (int j = t; j < NBUCK; j += 256) lc[j] = 0;
    __syncthreads();
    for (int e = blockIdx.x * 256 + t; e < N_EDGES; e += BC_BLOCKS * 256) {
        atomicAdd(&lc[dR[e] >> BSHIFT], 1);
        atomicAdd(&lc[(N_NODES + dX[e]) >> BSHIFT], 1);
    }
    __syncthreads();
    for (int j = t; j < NBUCK; j += 256) {
        int v = lc[j];
        if (v) atomicAdd(&bucketTotal[j], v);
    }
}

// ---------- pass 0b: scan 196 bucket totals (single block) ----------
__global__ __launch_bounds__(256) void bucket_scan(const int* __restrict__ bucketTotal,
                                                   int* __restrict__ bucketBase,
                                                   int* __restrict__ bucketCursor) {
    __shared__ int s[256];
    int t = threadIdx.x;
    int v = (t < NBUCK) ? bucketTotal[t] : 0;
    s[t] = v;
    __syncthreads();
    for (int off = 1; off < 256; off <<= 1) {
        int tv = (t >= off) ? s[t - off] : 0;
        __syncthreads();
        s[t] += tv;
        __syncthreads();
    }
    if (t < NBUCK) {
        int excl = s[t] - v;
        bucketBase[t] = excl;
        bucketCursor[t] = excl;
    }
    if (t == NBUCK - 1) bucketBase[NBUCK] = s[t];   // == E_ALL
}

// ---------- pass 1: bin u32 pairs (d_low9<<16 | src16) by bucket; coalesced runs ----------
__global__ __launch_bounds__(256) void bin_scatter(const int* __restrict__ sR,
                                                   const int* __restrict__ dR,
                                                   const int* __restrict__ sX,
                                                   const int* __restrict__ dX,
                                                   int* __restrict__ bucketCursor,
                                                   unsigned* __restrict__ pairs) {
    __shared__ unsigned lpair[CHUNK];
    __shared__ unsigned char lbuck[CHUNK];
    __shared__ int lcnt[NBUCK];
    __shared__ int lbase[NBUCK];
    __shared__ int gbase[NBUCK];
    __shared__ int sc[256];
    __shared__ int tot;
    int t = threadIdx.x;
    for (int j = t; j < NBUCK; j += 256) lcnt[j] = 0;
    __syncthreads();

    int base = blockIdx.x * CHUNK;
    unsigned myp[12];
    int myr[12], myb[12];
#pragma unroll
    for (int i = 0; i < 12; ++i) {
        int e = base + i * 256 + t;
        if (e < E_ALL) {
            bool isR = (e < N_EDGES);
            int d = isR ? dR[e] : (N_NODES + dX[e - N_EDGES]);
            int s = isR ? sR[e] : sX[e - N_EDGES];
            myp[i] = ((unsigned)(d & 511) << 16) | (unsigned)s;
            myb[i] = d >> BSHIFT;
            myr[i] = atomicAdd(&lcnt[myb[i]], 1);
        }
    }
    __syncthreads();

    int v = (t < NBUCK) ? lcnt[t] : 0;
    sc[t] = v;
    __syncthreads();
    for (int off = 1; off < 256; off <<= 1) {
        int tv = (t >= off) ? sc[t - off] : 0;
        __syncthreads();
        sc[t] += tv;
        __syncthreads();
    }
    if (t < NBUCK) {
        lbase[t] = sc[t] - v;
        if (v > 0) gbase[t] = atomicAdd(&bucketCursor[t], v);
    }
    if (t == NBUCK - 1) tot = sc[t];
    __syncthreads();

#pragma unroll
    for (int i = 0; i < 12; ++i) {
        int e = base + i * 256 + t;
        if (e < E_ALL) {
            int p = lbase[myb[i]] + myr[i];
            lpair[p] = myp[i];
            lbuck[p] = (unsigned char)myb[i];
        }
    }
    __syncthreads();

    int total = tot;
    for (int j = t; j < total; j += 256) {
        int b = lbuck[j];
        pairs[(size_t)gbase[b] + (j - lbase[b])] = lpair[j];
    }
}

// ---------- pass 2: per bucket -- degrees+rowptr in LDS, place col; writes coalesced ----------
__global__ __launch_bounds__(256) void bucket_place(const unsigned* __restrict__ pairs,
                                                    const int* __restrict__ bucketBase,
                                                    int* __restrict__ rowptr,
                                                    unsigned short* __restrict__ col) {
    __shared__ unsigned short scol[10240];
    __shared__ int ldeg[512];
    __shared__ int lcur[512];
    __shared__ int s1[256];
    int b = blockIdx.x;
    int d0 = b << BSHIFT;
    int nd = min(512, N_ALL - d0);
    int t = threadIdx.x;
    int base = bucketBase[b];
    int cnt = bucketBase[b + 1] - base;
    ldeg[t] = 0; ldeg[t + 256] = 0;
    __syncthreads();
    for (int i = t; i < cnt; i += 256) {
        int dl = pairs[(size_t)base + i] >> 16;
        atomicAdd(&ldeg[dl], 1);
    }
    __syncthreads();
    int v0 = ldeg[2 * t], v1 = ldeg[2 * t + 1];
    int pv = v0 + v1;
    s1[t] = pv;
    __syncthreads();
    for (int off = 1; off < 256; off <<= 1) {
        int tv = (t >= off) ? s1[t - off] : 0;
        __syncthreads();
        s1[t] += tv;
        __syncthreads();
    }
    int before = s1[t] - pv;
    lcur[2 * t] = before;
    lcur[2 * t + 1] = before + v0;
    if (2 * t < nd)     rowptr[d0 + 2 * t]     = base + before;
    if (2 * t + 1 < nd) rowptr[d0 + 2 * t + 1] = base + before + v0;
    if (b == NBUCK - 1 && t == 0) rowptr[N_ALL] = base + cnt;
    __syncthreads();
    for (int i = t; i < cnt; i += 256) {
        unsigned pr = pairs[(size_t)base + i];
        int dl = pr >> 16;
        int p = atomicAdd(&lcur[dl], 1);
        scol[p] = (unsigned short)(pr & 0xFFFFu);
    }
    __syncthreads();
    for (int i = t; i < cnt; i += 256) col[base + i] = scol[i];
}

// ---------- shared gather helper: a[8] += sum of neighbor rows (split-edge, unroll 8) ----------
__device__ __forceinline__ void gather_rows(const uint4* __restrict__ xb,
                                            const unsigned short* __restrict__ cp,
                                            int ch, int ln8, float* a) {
    int i = 0;
    for (; i + 8 <= ch; i += 8) {
        int s0 = cp[2 * i],      s1 = cp[2 * i + 2],  s2 = cp[2 * i + 4],  s3 = cp[2 * i + 6];
        int s4 = cp[2 * i + 8],  s5 = cp[2 * i + 10], s6 = cp[2 * i + 12], s7 = cp[2 * i + 14];
        uint4 v0 = xb[(size_t)s0 * 8 + ln8];
        uint4 v1 = xb[(size_t)s1 * 8 + ln8];
        uint4 v2 = xb[(size_t)s2 * 8 + ln8];
        uint4 v3 = xb[(size_t)s3 * 8 + ln8];
        uint4 v4 = xb[(size_t)s4 * 8 + ln8];
        uint4 v5 = xb[(size_t)s5 * 8 + ln8];
        uint4 v6 = xb[(size_t)s6 * 8 + ln8];
        uint4 v7 = xb[(size_t)s7 * 8 + ln8];
        acc8(a, v0); acc8(a, v1); acc8(a, v2); acc8(a, v3);
        acc8(a, v4); acc8(a, v5); acc8(a, v6); acc8(a, v7);
    }
    for (; i + 4 <= ch; i += 4) {
        int s0 = cp[2 * i], s1 = cp[2 * i + 2], s2 = cp[2 * i + 4], s3 = cp[2 * i + 6];
        uint4 v0 = xb[(size_t)s0 * 8 + ln8];
        uint4 v1 = xb[(size_t)s1 * 8 + ln8];
        uint4 v2 = xb[(size_t)s2 * 8 + ln8];
        uint4 v3 = xb[(size_t)s3 * 8 + ln8];
        acc8(a, v0); acc8(a, v1); acc8(a, v2); acc8(a, v3);
    }
    for (; i < ch; ++i) acc8(a, xb[(size_t)cp[2 * i] * 8 + ln8]);
}

// ---------- split-edge bf16 gather, unroll 8 ----------
__global__ __launch_bounds__(256, 8) void gather_bf16(const uint4* __restrict__ xb,
                                                      uint4* __restrict__ ob,
                                                      const int* __restrict__ rowptr,
                                                      const unsigned short* __restrict__ col) {
    int t = threadIdx.x;
    int grp = t >> 4;
    int half = (t >> 3) & 1;
    int ln8 = t & 7;
    int node = blockIdx.x * 16 + grp;   // grid exactly covers 50000
    int beg = rowptr[node], end = rowptr[node + 1];
    int cnt = end - beg;
    int ch = (cnt - half + 1) >> 1;
    const unsigned short* cp = col + beg + half;
    float a[8];
    if (half == 0) {
        uint4 v = xb[(size_t)node * 8 + ln8];
        a[0] = bflo(v.x); a[1] = bfhi(v.x); a[2] = bflo(v.y); a[3] = bfhi(v.y);
        a[4] = bflo(v.z); a[5] = bfhi(v.z); a[6] = bflo(v.w); a[7] = bfhi(v.w);
    } else {
#pragma unroll
        for (int i = 0; i < 8; ++i) a[i] = 0.0f;
    }
    gather_rows(xb, cp, ch, ln8, a);
#pragma unroll
    for (int j = 0; j < 8; ++j) a[j] += __shfl_xor(a[j], 8);
    if (half == 0) {
        uint4 o;
        o.x = f2bf(a[0]) | (f2bf(a[1]) << 16);
        o.y = f2bf(a[2]) | (f2bf(a[3]) << 16);
        o.z = f2bf(a[4]) | (f2bf(a[5]) << 16);
        o.w = f2bf(a[6]) | (f2bf(a[7]) << 16);
        ob[(size_t)node * 8 + ln8] = o;
    }
}

// ---------- fused: y = relu( (x + gather(x)) @ W^T + b ) -- MFMA MLP ----------
// Per block: 16 nodes. h[16][64] (bf16, LDS) @ W^T via 4 waves x 2 mfma_f32_16x16x32_bf16.
// Fragment maps (m89-verified C/D; A/B lane-group k-permutation cancels between A and B):
//   A: lane l -> h[l&15][(l>>4)*8 + j + kk*32]      (1 ds_read_b128)
//   B: lane l -> W^T[k][wv*16 + (l&15)] = W[o][k]   (precomputed in LDS, 1 ds_read_b128)
//   D: lane l, reg r -> y_pre[node=(l>>4)*4+r][o=wv*16+(l&15)]
__global__ __launch_bounds__(256, 6) void gather_linear(const uint4* __restrict__ xb,
                                                        unsigned short* __restrict__ y,
                                                        const int* __restrict__ rowptr,
                                                        const unsigned short* __restrict__ col,
                                                        const float* __restrict__ W,
                                                        const float* __restrict__ b) {
    __shared__ __align__(16) unsigned short hlb[16 * 72];       // h bf16, stride 72 (conflict-free)
    __shared__ __align__(16) unsigned short Wb[4 * 2 * 64 * 8]; // B-frags [wave][kk][lane][8]
    int t = threadIdx.x;
    int wv = t >> 6, lane = t & 63;
    int lo16 = lane & 15, hi4 = lane >> 4;

    // ---- B-fragment precompute: Wb[wv][kk][lane][j] = W[wv*16+lo16][kk*32+hi4*8+j] ----
    {
        const float* wp = W + (wv * 16 + lo16) * 64 + hi4 * 8;
#pragma unroll
        for (int kk = 0; kk < 2; ++kk) {
            float4 w0 = *(const float4*)(wp + kk * 32);
            float4 w1 = *(const float4*)(wp + kk * 32 + 4);
            uint4 pk;
            pk.x = f2bf(w0.x) | (f2bf(w0.y) << 16);
            pk.y = f2bf(w0.z) | (f2bf(w0.w) << 16);
            pk.z = f2bf(w1.x) | (f2bf(w1.y) << 16);
            pk.w = f2bf(w1.z) | (f2bf(w1.w) << 16);
            *(uint4*)&Wb[((wv * 2 + kk) * 64 + lane) * 8] = pk;
        }
    }

    // ---- gather phase (unchanged): h = x + sum_{j in N} x_j ----
    int grp = t >> 4;
    int half = (t >> 3) & 1;
    int ln8 = t & 7;
    int node = blockIdx.x * 16 + grp;   // grid exactly covers 50000
    int beg = rowptr[node], end = rowptr[node + 1];
    int cnt = end - beg;
    int ch = (cnt - half + 1) >> 1;
    const unsigned short* cp = col + beg + half;
    float a[8];
    if (half == 0) {
        uint4 v = xb[(size_t)node * 8 + ln8];
        a[0] = bflo(v.x); a[1] = bfhi(v.x); a[2] = bflo(v.y); a[3] = bfhi(v.y);
        a[4] = bflo(v.z); a[5] = bfhi(v.z); a[6] = bflo(v.w); a[7] = bfhi(v.w);
    } else {
#pragma unroll
        for (int i = 0; i < 8; ++i) a[i] = 0.0f;
    }
    gather_rows(xb, cp, ch, ln8, a);
#pragma unroll
    for (int j = 0; j < 8; ++j) a[j] += __shfl_xor(a[j], 8);
    if (half == 0) {
        uint4 o4;
        o4.x = f2bf(a[0]) | (f2bf(a[1]) << 16);
        o4.y = f2bf(a[2]) | (f2bf(a[3]) << 16);
        o4.z = f2bf(a[4]) | (f2bf(a[5]) << 16);
        o4.w = f2bf(a[6]) | (f2bf(a[7]) << 16);
        *(uint4*)&hlb[grp * 72 + ln8 * 8] = o4;   // 16B, conflict-free (stride 72)
    }
    __syncthreads();

    // ---- MFMA MLP: 2 x mfma_f32_16x16x32_bf16 per wave ----
    f32x4 acc = {0.0f, 0.0f, 0.0f, 0.0f};
    bf16x8 a0 = *(const bf16x8*)&hlb[lo16 * 72 + hi4 * 8];
    bf16x8 a1 = *(const bf16x8*)&hlb[lo16 * 72 + 32 + hi4 * 8];
    bf16x8 b0 = *(const bf16x8*)&Wb[((wv * 2 + 0) * 64 + lane) * 8];
    bf16x8 b1 = *(const bf16x8*)&Wb[((wv * 2 + 1) * 64 + lane) * 8];
    acc = __builtin_amdgcn_mfma_f32_16x16x32_bf16(a0, b0, acc, 0, 0, 0);
    acc = __builtin_amdgcn_mfma_f32_16x16x32_bf16(a1, b1, acc, 0, 0, 0);

    int o = wv * 16 + lo16;
    float bo = b[o];
    size_t nbase = (size_t)blockIdx.x * 16;
#pragma unroll
    for (int r = 0; r < 4; ++r) {
        int nr = hi4 * 4 + r;
        y[(nbase + nr) * 64 + o] = (unsigned short)f2bf(fmaxf(acc[r] + bo, 0.0f));
    }
}

// ---------- pool: batch sorted -> contiguous segments ----------
__device__ __forceinline__ int lower_bound_dev(const int* __restrict__ a, int n, int v) {
    int lo = 0, hi = n;
    while (lo < hi) { int mid = (lo + hi) >> 1; if (a[mid] < v) lo = mid + 1; else hi = mid; }
    return lo;
}

__global__ __launch_bounds__(256) void pool_seg_bf16(const unsigned short* __restrict__ xb,
                                                     const int* __restrict__ batch,
                                                     float* __restrict__ out) {
    int g = blockIdx.x;
    int lo = lower_bound_dev(batch, N_NODES, g);
    int hi = lower_bound_dev(batch, N_NODES, g + 1);
    int lane = threadIdx.x & 63;
    int sub = threadIdx.x >> 6;
    float acc = 0.0f;
    for (int n = lo + sub; n < hi; n += 4)
        acc += __uint_as_float(((unsigned)xb[(size_t)n * 64 + lane]) << 16);
    __shared__ float red[256];
    red[threadIdx.x] = acc;
    __syncthreads();
    if (sub == 0)
        out[(size_t)g * D + lane] = red[lane] + red[64 + lane] + red[128 + lane] + red[192 + lane];
}

// ---------- host ----------
extern "C" void kernel_launch(void* const* d_in, const int* in_sizes, int n_in,
                              void* d_out, int out_size, void* d_ws, size_t ws_size,
                              hipStream_t stream) {
    const float* x_in  = (const float*)d_in[0];
    const int*   ei    = (const int*)d_in[1];
    const int*   eei   = (const int*)d_in[2];
    const int*   batch = (const int*)d_in[3];
    const float* Ws    = (const float*)d_in[4];
    const float* bs    = (const float*)d_in[5];
    float* out = (float*)d_out;

    unsigned short* A = (unsigned short*)d_ws;          // y (bf16) [N*D]
    unsigned short* B = A + (size_t)N_NODES * D;        // x / x' (bf16)
    unsigned short* colAll = B + (size_t)N_NODES * D;   // u16 col [E_ALL]
    unsigned* pairs = (unsigned*)(colAll + E_ALL);      // u32 pairs [E_ALL]
    int* p = (int*)(pairs + E_ALL);
    int* rowptr = p;        p += N_ALL + 1;
    int* bucketTotal = p;   p += NBUCK;
    int* bucketBase = p;    p += NBUCK + 1;
    int* bucketCursor = p;  p += NBUCK;

    const int* e_src = ei;
    const int* e_dst = ei + N_EDGES;
    const int* x_src = eei;
    const int* x_dst = eei + N_EDGES;

    dim3 blk(256);

    // input fp32 -> bf16 (into B); also zeroes bucketTotal (replaces memset dispatch)
    const int cgrid = (N_NODES * D / 8 + 255) / 256;   // 1563
    x_to_bf16<<<cgrid, blk, 0, stream>>>((const float4*)x_in, (uint4*)B, bucketTotal);

    // CSR build: bucket totals -> scan -> bucketed u32-pair sort -> per-bucket rowptr+col
    bucket_count<<<BC_BLOCKS, blk, 0, stream>>>(e_dst, x_dst, bucketTotal);
    bucket_scan<<<1, blk, 0, stream>>>(bucketTotal, bucketBase, bucketCursor);
    bin_scatter<<<NCHUNK, blk, 0, stream>>>(e_src, e_dst, x_src, x_dst, bucketCursor, pairs);
    bucket_place<<<NBUCK, blk, 0, stream>>>(pairs, bucketBase, rowptr, colAll);

    const int lgrid = N_NODES / 16;            // 3125, exact

    // all 4 layers uniform bf16: gather_linear(B->A) then expander gather_bf16(A->B)
    for (int i = 0; i < NUM_LAYERS; ++i) {
        gather_linear<<<lgrid, blk, 0, stream>>>((const uint4*)B, A,
                                                 rowptr, colAll,
                                                 Ws + (size_t)i * D * D,
                                                 bs + (size_t)i * D);
        gather_bf16<<<lgrid, blk, 0, stream>>>((const uint4*)A, (uint4*)B,
                                               rowptr + N_NODES, colAll);
    }

    pool_seg_bf16<<<NUM_GRAPHS, blk, 0, stream>>>(B, batch, out);
}